// Round 1
// baseline (320.305 us; speedup 1.0000x reference)
//
#include <hip/hip_runtime.h>
#include <math.h>

#define N_NODES 50000
#define N_EDGES 800000
#define IN_CH 64
#define OUT_CH 32
#define HEADS 4
#define HC 128            // HEADS*OUT_CH
#define NEG_SLOPE 0.2f
#define SOFT_EPS 1e-16f

// ---------------- kernel 1: fold W_edge x att_edge -> v_edge[4][64] ----------------
// v_edge[h][k] = sum_c att_edge[h][c] * W_edge[h*32+c][k]
__global__ void k_prep(const float* __restrict__ W_edge,
                       const float* __restrict__ att_edge,
                       float* __restrict__ v_edge) {
    int t = threadIdx.x;          // 256 threads = 4 heads * 64 k
    int h = t >> 6, k = t & 63;
    float s = 0.f;
    #pragma unroll
    for (int c = 0; c < OUT_CH; ++c)
        s += att_edge[h * OUT_CH + c] * W_edge[(h * OUT_CH + c) * IN_CH + k];
    v_edge[h * IN_CH + k] = s;
}

// ---------------- kernel 2: xh = x @ W^T, plus per-node attention scalars ----------
// One wave handles 8 nodes; lane l computes outputs o=l and o=64+l.
__global__ __launch_bounds__(256) void k_node(const float* __restrict__ x,
                                              const float* __restrict__ W,
                                              const float* __restrict__ att_src,
                                              const float* __restrict__ att_dst,
                                              float* __restrict__ xh,
                                              float* __restrict__ a_src,
                                              float* __restrict__ a_dst) {
    __shared__ float Wl[HC * 65];          // +1 pad -> bank (l + k) % 32, 2-way = free
    int tid = threadIdx.x;
    for (int i = tid; i < HC * IN_CH; i += 256)
        Wl[(i >> 6) * 65 + (i & 63)] = W[i];
    __syncthreads();

    int w = tid >> 6, l = tid & 63;
    float as0 = att_src[l], as1 = att_src[64 + l];
    float ad0 = att_dst[l], ad1 = att_dst[64 + l];
    int nbase = blockIdx.x * 32 + w * 8;

    for (int t = 0; t < 8; ++t) {
        int n = nbase + t;
        if (n >= N_NODES) break;
        const float4* xr = (const float4*)(x + (size_t)n * IN_CH);
        float4 A0 = {0, 0, 0, 0}, A1 = {0, 0, 0, 0};
        #pragma unroll
        for (int k4 = 0; k4 < 16; ++k4) {
            float4 xv = xr[k4];              // broadcast: all lanes same address
            int k = k4 * 4;
            const float* w0 = &Wl[l * 65 + k];
            const float* w1 = &Wl[(64 + l) * 65 + k];
            A0.x += xv.x * w0[0]; A0.y += xv.y * w0[1];
            A0.z += xv.z * w0[2]; A0.w += xv.w * w0[3];
            A1.x += xv.x * w1[0]; A1.y += xv.y * w1[1];
            A1.z += xv.z * w1[2]; A1.w += xv.w * w1[3];
        }
        float acc0 = (A0.x + A0.y) + (A0.z + A0.w);
        float acc1 = (A1.x + A1.y) + (A1.z + A1.w);
        xh[(size_t)n * HC + l]      = acc0;
        xh[(size_t)n * HC + 64 + l] = acc1;

        // per-node attention scalars: a_src[n][h] = sum_c xh[n][h*32+c]*att_src[h][c]
        float p  = acc0 * as0, q  = acc1 * as1;   // heads (l>>5), 2+(l>>5)
        float pd = acc0 * ad0, qd = acc1 * ad1;
        #pragma unroll
        for (int m = 1; m <= 16; m <<= 1) {       // reduce within 32-lane halves
            p  += __shfl_xor(p,  m, 64);
            q  += __shfl_xor(q,  m, 64);
            pd += __shfl_xor(pd, m, 64);
            qd += __shfl_xor(qd, m, 64);
        }
        if (l == 0) {
            a_src[n * 4 + 0] = p;  a_src[n * 4 + 2] = q;
            a_dst[n * 4 + 0] = pd; a_dst[n * 4 + 2] = qd;
        } else if (l == 32) {
            a_src[n * 4 + 1] = p;  a_src[n * 4 + 3] = q;
            a_dst[n * 4 + 1] = pd; a_dst[n * 4 + 3] = qd;
        }
    }
}

// ---------------- kernel 3: per-edge logits + degree histogram ---------------------
// 4 threads per edge, 64 edges per 256-thread block. Fully-coalesced 205 MB read.
__global__ __launch_bounds__(256) void k_edge(const float* __restrict__ edge_attr,
                                              const int* __restrict__ srcI,
                                              const int* __restrict__ dstI,
                                              const float* __restrict__ v_edge,
                                              const float* __restrict__ a_src,
                                              const float* __restrict__ a_dst,
                                              float* __restrict__ alpha_raw,
                                              int* __restrict__ deg) {
    __shared__ float vl[4 * IN_CH];
    int tid = threadIdx.x;
    vl[tid] = v_edge[tid];
    __syncthreads();
    int el = tid >> 2, part = tid & 3;
    long e = (long)blockIdx.x * 64 + el;
    if (e >= N_EDGES) return;

    const float4* ea = (const float4*)(edge_attr + e * IN_CH + part * 16);
    float4 v0 = ea[0], v1 = ea[1], v2 = ea[2], v3 = ea[3];
    float p[4];
    #pragma unroll
    for (int h = 0; h < 4; ++h) {
        const float* vr = vl + h * IN_CH + part * 16;
        p[h] = v0.x * vr[0]  + v0.y * vr[1]  + v0.z * vr[2]  + v0.w * vr[3]
             + v1.x * vr[4]  + v1.y * vr[5]  + v1.z * vr[6]  + v1.w * vr[7]
             + v2.x * vr[8]  + v2.y * vr[9]  + v2.z * vr[10] + v2.w * vr[11]
             + v3.x * vr[12] + v3.y * vr[13] + v3.z * vr[14] + v3.w * vr[15];
    }
    #pragma unroll
    for (int h = 0; h < 4; ++h) {             // reduce across the 4 lanes of this edge
        p[h] += __shfl_xor(p[h], 1, 64);
        p[h] += __shfl_xor(p[h], 2, 64);
    }
    int d = dstI[e], s = srcI[e];
    float logit = a_src[d * 4 + part] + a_dst[s * 4 + part] + p[part];
    float lr = logit > 0.f ? logit : NEG_SLOPE * logit;
    alpha_raw[e * 4 + part] = lr;             // head = part
    if (part == 0) atomicAdd(&deg[d], 1);
}

// ---------------- scan kernels: exclusive prefix sum of deg -> offs ----------------
__global__ void k_scan1(const int* __restrict__ deg, int* __restrict__ offs,
                        int* __restrict__ bsum) {
    __shared__ int tmp[256];
    int t = threadIdx.x;
    int i = blockIdx.x * 256 + t;
    int v = (i < N_NODES) ? deg[i] : 0;
    tmp[t] = v;
    __syncthreads();
    #pragma unroll
    for (int off = 1; off < 256; off <<= 1) {
        int xv = (t >= off) ? tmp[t - off] : 0;
        __syncthreads();
        tmp[t] += xv;
        __syncthreads();
    }
    if (i < N_NODES) offs[i] = tmp[t] - v;    // exclusive
    if (t == 255) bsum[blockIdx.x] = tmp[t];
}

__global__ void k_scan2(const int* __restrict__ bsum, int* __restrict__ bbase, int nb) {
    __shared__ int tmp[256];
    int t = threadIdx.x;
    int v = (t < nb) ? bsum[t] : 0;
    tmp[t] = v;
    __syncthreads();
    #pragma unroll
    for (int off = 1; off < 256; off <<= 1) {
        int xv = (t >= off) ? tmp[t - off] : 0;
        __syncthreads();
        tmp[t] += xv;
        __syncthreads();
    }
    bbase[t] = tmp[t] - v;                    // exclusive
}

__global__ void k_scan3(int* __restrict__ offs, const int* __restrict__ bbase) {
    int i = blockIdx.x * 256 + threadIdx.x;
    if (i < N_NODES) offs[i] += bbase[blockIdx.x];
}

// ---------------- kernel 5: CSR scatter ----------------
__global__ void k_scatter(const int* __restrict__ dstI, const int* __restrict__ offs,
                          int* __restrict__ cursor, int* __restrict__ elist) {
    int e = blockIdx.x * 256 + threadIdx.x;
    if (e >= N_EDGES) return;
    int d = dstI[e];
    int p = atomicAdd(&cursor[d], 1);
    elist[offs[d] + p] = e;
}

// ---------------- kernel 6: per-node softmax + weighted aggregation ----------------
// One 64-lane wave per dst node. Lane l owns channels (2l, 2l+1) of [H=4,C=32]=128.
__global__ __launch_bounds__(256) void k_aggr(const int* __restrict__ elist,
                                              const int* __restrict__ offs,
                                              const int* __restrict__ deg,
                                              const int* __restrict__ srcI,
                                              const float* __restrict__ alpha_raw,
                                              const float* __restrict__ xh,
                                              const float* __restrict__ bias_conv,
                                              const float* __restrict__ bias_layer,
                                              float* __restrict__ out) {
    int w = threadIdx.x >> 6, l = threadIdx.x & 63;
    int i = blockIdx.x * 4 + w;
    if (i >= N_NODES) return;
    int start = offs[i], cnt = deg[i];

    // ---- pass 1: online softmax (max, sum). lane handles head l&3, edges (l>>2)+16k
    int h1 = l & 3;
    float m = -3.402823466e38f, s = 0.f;
    for (int j = l >> 2; j < cnt; j += 16) {
        int e = elist[start + j];
        float al = alpha_raw[e * 4 + h1];
        float mn = fmaxf(m, al);
        s = s * __expf(m - mn) + __expf(al - mn);
        m = mn;
    }
    #pragma unroll
    for (int msk = 4; msk <= 32; msk <<= 1) {  // combine lanes with equal h1
        float mo = __shfl_xor(m, msk, 64);
        float so = __shfl_xor(s, msk, 64);
        float mn = fmaxf(m, mo);
        s = s * __expf(m - mn) + so * __expf(mo - mn);
        m = mn;
    }
    int h0 = l >> 4;                           // head of this lane's channel pair
    float m2 = __shfl(m, h0, 64);              // lane h0 (0..3) holds head h0's result
    float s2 = __shfl(s, h0, 64);
    float inv = 1.f / (s2 + SOFT_EPS);

    // ---- pass 2: weighted accumulate of xh[src] rows (coalesced 512B per edge)
    float ax = 0.f, ay = 0.f;
    if (cnt > 0) {
        int e = elist[start];
        for (int j = 0; j < cnt; ++j) {
            int en = (j + 1 < cnt) ? elist[start + j + 1] : 0;  // prefetch next id
            int sn = srcI[e];
            float al = alpha_raw[e * 4 + h0];
            float2 xv = ((const float2*)(xh + (size_t)sn * HC))[l];
            float wgt = __expf(al - m2) * inv;
            ax += wgt * xv.x;
            ay += wgt * xv.y;
            e = en;
        }
    }
    // ---- reduce over heads (lanes l, l^16, l^32, l^48 share channel c=2*(l&15))
    ax += __shfl_xor(ax, 16, 64); ax += __shfl_xor(ax, 32, 64);
    ay += __shfl_xor(ay, 16, 64); ay += __shfl_xor(ay, 32, 64);
    if (l < 16) {
        int c0 = 2 * l;
        float r0 = 0.25f * ax + bias_conv[c0]     + bias_layer[c0];
        float r1 = 0.25f * ay + bias_conv[c0 + 1] + bias_layer[c0 + 1];
        float2 o2 = {fmaxf(r0, 0.f), fmaxf(r1, 0.f)};
        ((float2*)(out + (size_t)i * OUT_CH))[l] = o2;
    }
}

extern "C" void kernel_launch(void* const* d_in, const int* in_sizes, int n_in,
                              void* d_out, int out_size, void* d_ws, size_t ws_size,
                              hipStream_t stream) {
    const float* x          = (const float*)d_in[0];
    const float* edge_attr  = (const float*)d_in[1];
    const float* W          = (const float*)d_in[2];
    const float* W_edge     = (const float*)d_in[3];
    const float* att_src    = (const float*)d_in[4];
    const float* att_dst    = (const float*)d_in[5];
    const float* att_edge   = (const float*)d_in[6];
    const float* bias_conv  = (const float*)d_in[7];
    const float* bias_layer = (const float*)d_in[8];
    const int*   edge_index = (const int*)d_in[9];
    const int* srcI = edge_index;                // edge_index[0]
    const int* dstI = edge_index + N_EDGES;      // edge_index[1]
    float* out = (float*)d_out;

    char* ws = (char*)d_ws;
    size_t off = 0;
    auto carve = [&](size_t bytes) -> char* {
        char* p = ws + off;
        off += (bytes + 255) & ~(size_t)255;
        return p;
    };
    float* xh        = (float*)carve((size_t)N_NODES * HC * 4);     // 25.6 MB
    float* alpha_raw = (float*)carve((size_t)N_EDGES * 4 * 4);      // 12.8 MB
    float* a_src     = (float*)carve((size_t)N_NODES * 4 * 4);
    float* a_dst     = (float*)carve((size_t)N_NODES * 4 * 4);
    float* v_edge    = (float*)carve(4 * IN_CH * 4);
    int*   deg       = (int*)carve((size_t)N_NODES * 4);
    int*   offs      = (int*)carve((size_t)N_NODES * 4);
    int*   cursor    = (int*)carve((size_t)N_NODES * 4);
    int*   bsum      = (int*)carve(256 * 4);
    int*   bbase     = (int*)carve(256 * 4);
    int*   elist     = (int*)carve((size_t)N_EDGES * 4);            // 3.2 MB

    hipMemsetAsync(deg, 0, (size_t)N_NODES * 4, stream);
    hipMemsetAsync(cursor, 0, (size_t)N_NODES * 4, stream);

    k_prep<<<1, 256, 0, stream>>>(W_edge, att_edge, v_edge);
    k_node<<<(N_NODES + 31) / 32, 256, 0, stream>>>(x, W, att_src, att_dst,
                                                    xh, a_src, a_dst);
    k_edge<<<(N_EDGES + 63) / 64, 256, 0, stream>>>(edge_attr, srcI, dstI, v_edge,
                                                    a_src, a_dst, alpha_raw, deg);
    int nb = (N_NODES + 255) / 256;
    k_scan1<<<nb, 256, 0, stream>>>(deg, offs, bsum);
    k_scan2<<<1, 256, 0, stream>>>(bsum, bbase, nb);
    k_scan3<<<nb, 256, 0, stream>>>(offs, bbase);
    k_scatter<<<(N_EDGES + 255) / 256, 256, 0, stream>>>(dstI, offs, cursor, elist);
    k_aggr<<<(N_NODES + 3) / 4, 256, 0, stream>>>(elist, offs, deg, srcI, alpha_raw,
                                                  xh, bias_conv, bias_layer, out);
}

// Round 2
// 246.667 us; speedup vs baseline: 1.2985x; 1.2985x over previous
//
#include <hip/hip_runtime.h>
#include <hip/hip_fp16.h>
#include <math.h>

#define N_NODES 50000
#define N_EDGES 800000
#define IN_CH 64
#define OUT_CH 32
#define HEADS 4
#define HC 128            // HEADS*OUT_CH
#define NEG_SLOPE 0.2f
#define SOFT_EPS 1e-16f
#define NEG_INF -3.402823466e38f

// ---------------- kernel 1: fold W_edge x att_edge -> v_edge[4][64] ----------------
__global__ void k_prep(const float* __restrict__ W_edge,
                       const float* __restrict__ att_edge,
                       float* __restrict__ v_edge) {
    int t = threadIdx.x;          // 256 threads = 4 heads * 64 k
    int h = t >> 6, k = t & 63;
    float s = 0.f;
    #pragma unroll
    for (int c = 0; c < OUT_CH; ++c)
        s += att_edge[h * OUT_CH + c] * W_edge[(h * OUT_CH + c) * IN_CH + k];
    v_edge[h * IN_CH + k] = s;
}

// ---------------- kernel 2: xh16 = fp16(x @ W^T), plus per-node att scalars --------
__global__ __launch_bounds__(256) void k_node(const float* __restrict__ x,
                                              const float* __restrict__ W,
                                              const float* __restrict__ att_src,
                                              const float* __restrict__ att_dst,
                                              __half* __restrict__ xh16,
                                              float* __restrict__ a_src,
                                              float* __restrict__ a_dst) {
    __shared__ float Wl[HC * 65];          // +1 pad
    int tid = threadIdx.x;
    for (int i = tid; i < HC * IN_CH; i += 256)
        Wl[(i >> 6) * 65 + (i & 63)] = W[i];
    __syncthreads();

    int w = tid >> 6, l = tid & 63;
    float as0 = att_src[l], as1 = att_src[64 + l];
    float ad0 = att_dst[l], ad1 = att_dst[64 + l];
    int nbase = blockIdx.x * 32 + w * 8;

    for (int t = 0; t < 8; ++t) {
        int n = nbase + t;
        if (n >= N_NODES) break;
        const float4* xr = (const float4*)(x + (size_t)n * IN_CH);
        float4 A0 = {0, 0, 0, 0}, A1 = {0, 0, 0, 0};
        #pragma unroll
        for (int k4 = 0; k4 < 16; ++k4) {
            float4 xv = xr[k4];              // broadcast
            int k = k4 * 4;
            const float* w0 = &Wl[l * 65 + k];
            const float* w1 = &Wl[(64 + l) * 65 + k];
            A0.x += xv.x * w0[0]; A0.y += xv.y * w0[1];
            A0.z += xv.z * w0[2]; A0.w += xv.w * w0[3];
            A1.x += xv.x * w1[0]; A1.y += xv.y * w1[1];
            A1.z += xv.z * w1[2]; A1.w += xv.w * w1[3];
        }
        float acc0 = (A0.x + A0.y) + (A0.z + A0.w);
        float acc1 = (A1.x + A1.y) + (A1.z + A1.w);
        xh16[(size_t)n * HC + l]      = __float2half(acc0);
        xh16[(size_t)n * HC + 64 + l] = __float2half(acc1);

        float p  = acc0 * as0, q  = acc1 * as1;
        float pd = acc0 * ad0, qd = acc1 * ad1;
        #pragma unroll
        for (int m = 1; m <= 16; m <<= 1) {
            p  += __shfl_xor(p,  m, 64);
            q  += __shfl_xor(q,  m, 64);
            pd += __shfl_xor(pd, m, 64);
            qd += __shfl_xor(qd, m, 64);
        }
        if (l == 0) {
            a_src[n * 4 + 0] = p;  a_src[n * 4 + 2] = q;
            a_dst[n * 4 + 0] = pd; a_dst[n * 4 + 2] = qd;
        } else if (l == 32) {
            a_src[n * 4 + 1] = p;  a_src[n * 4 + 3] = q;
            a_dst[n * 4 + 1] = pd; a_dst[n * 4 + 3] = qd;
        }
    }
}

// ---------------- kernel 3: degree histogram ----------------
__global__ void k_deg(const int* __restrict__ dstI, int* __restrict__ deg) {
    int e = blockIdx.x * 256 + threadIdx.x;
    if (e < N_EDGES) atomicAdd(&deg[dstI[e]], 1);
}

// ---------------- scan kernels: exclusive prefix sum of deg -> offs ----------------
__global__ void k_scan1(const int* __restrict__ deg, int* __restrict__ offs,
                        int* __restrict__ bsum) {
    __shared__ int tmp[256];
    int t = threadIdx.x;
    int i = blockIdx.x * 256 + t;
    int v = (i < N_NODES) ? deg[i] : 0;
    tmp[t] = v;
    __syncthreads();
    #pragma unroll
    for (int off = 1; off < 256; off <<= 1) {
        int xv = (t >= off) ? tmp[t - off] : 0;
        __syncthreads();
        tmp[t] += xv;
        __syncthreads();
    }
    if (i < N_NODES) offs[i] = tmp[t] - v;    // exclusive
    if (t == 255) bsum[blockIdx.x] = tmp[t];
}

__global__ void k_scan2(const int* __restrict__ bsum, int* __restrict__ bbase, int nb) {
    __shared__ int tmp[256];
    int t = threadIdx.x;
    int v = (t < nb) ? bsum[t] : 0;
    tmp[t] = v;
    __syncthreads();
    #pragma unroll
    for (int off = 1; off < 256; off <<= 1) {
        int xv = (t >= off) ? tmp[t - off] : 0;
        __syncthreads();
        tmp[t] += xv;
        __syncthreads();
    }
    bbase[t] = tmp[t] - v;                    // exclusive
}

__global__ void k_scan3(int* __restrict__ offs, const int* __restrict__ bbase) {
    int i = blockIdx.x * 256 + threadIdx.x;
    if (i < N_NODES) offs[i] += bbase[blockIdx.x];
}

// ---------------- kernel 4: edge logits + fused CSR scatter ------------------------
// 4 threads per edge (part = head). Writes alpha and src ALREADY in CSR order.
__global__ __launch_bounds__(256) void k_edge(const float* __restrict__ edge_attr,
                                              const int* __restrict__ srcI,
                                              const int* __restrict__ dstI,
                                              const float* __restrict__ v_edge,
                                              const float* __restrict__ a_src,
                                              const float* __restrict__ a_dst,
                                              const int* __restrict__ offs,
                                              int* __restrict__ cursor,
                                              float* __restrict__ alpha_perm,
                                              int* __restrict__ src_perm) {
    __shared__ float vl[4 * IN_CH];
    int tid = threadIdx.x;
    vl[tid] = v_edge[tid];
    __syncthreads();
    int el = tid >> 2, part = tid & 3, l = tid & 63;
    long e = (long)blockIdx.x * 64 + el;
    if (e >= N_EDGES) return;

    const float4* ea = (const float4*)(edge_attr + e * IN_CH + part * 16);
    float4 v0 = ea[0], v1 = ea[1], v2 = ea[2], v3 = ea[3];
    float p[4];
    #pragma unroll
    for (int h = 0; h < 4; ++h) {
        const float* vr = vl + h * IN_CH + part * 16;
        p[h] = v0.x * vr[0]  + v0.y * vr[1]  + v0.z * vr[2]  + v0.w * vr[3]
             + v1.x * vr[4]  + v1.y * vr[5]  + v1.z * vr[6]  + v1.w * vr[7]
             + v2.x * vr[8]  + v2.y * vr[9]  + v2.z * vr[10] + v2.w * vr[11]
             + v3.x * vr[12] + v3.y * vr[13] + v3.z * vr[14] + v3.w * vr[15];
    }
    #pragma unroll
    for (int h = 0; h < 4; ++h) {
        p[h] += __shfl_xor(p[h], 1, 64);
        p[h] += __shfl_xor(p[h], 2, 64);
    }
    int d = dstI[e], s = srcI[e];
    float logit = a_src[d * 4 + part] + a_dst[s * 4 + part] + p[part];
    float lr = logit > 0.f ? logit : NEG_SLOPE * logit;

    int pos = 0;
    if (part == 0) pos = offs[d] + atomicAdd(&cursor[d], 1);
    pos = __shfl(pos, l & ~3, 64);            // broadcast from part==0 lane
    alpha_perm[(size_t)pos * 4 + part] = lr;
    if (part == 0) src_perm[pos] = s;
}

// ---------------- kernel 5: single-pass online softmax + aggregation ---------------
// One 64-lane wave per dst node. Lane l owns channels (2l,2l+1); head h0 = l>>4.
__global__ __launch_bounds__(256) void k_aggr(const float* __restrict__ alpha_perm,
                                              const int* __restrict__ src_perm,
                                              const int* __restrict__ offs,
                                              const int* __restrict__ deg,
                                              const __half* __restrict__ xh16,
                                              const float* __restrict__ bias_conv,
                                              const float* __restrict__ bias_layer,
                                              float* __restrict__ out) {
    int w = threadIdx.x >> 6, l = threadIdx.x & 63;
    int i = blockIdx.x * 4 + w;
    if (i >= N_NODES) return;
    int start = offs[i], cnt = deg[i];
    int h0 = l >> 4;

    float m = NEG_INF, s = 0.f, ax = 0.f, ay = 0.f;
    int cnt4 = cnt & ~3;
    for (int j = 0; j < cnt4; j += 4) {
        int base = start + j;
        float a0 = alpha_perm[(size_t)(base + 0) * 4 + h0];
        float a1 = alpha_perm[(size_t)(base + 1) * 4 + h0];
        float a2 = alpha_perm[(size_t)(base + 2) * 4 + h0];
        float a3 = alpha_perm[(size_t)(base + 3) * 4 + h0];
        int s0 = src_perm[base + 0], s1 = src_perm[base + 1];
        int s2 = src_perm[base + 2], s3 = src_perm[base + 3];
        __half2 h0v = ((const __half2*)(xh16 + (size_t)s0 * HC))[l];
        __half2 h1v = ((const __half2*)(xh16 + (size_t)s1 * HC))[l];
        __half2 h2v = ((const __half2*)(xh16 + (size_t)s2 * HC))[l];
        __half2 h3v = ((const __half2*)(xh16 + (size_t)s3 * HC))[l];
        float mn = fmaxf(fmaxf(fmaxf(a0, a1), fmaxf(a2, a3)), m);
        float e0 = __expf(a0 - mn), e1 = __expf(a1 - mn);
        float e2 = __expf(a2 - mn), e3 = __expf(a3 - mn);
        float sc = __expf(m - mn);
        float2 f0 = __half22float2(h0v), f1 = __half22float2(h1v);
        float2 f2 = __half22float2(h2v), f3 = __half22float2(h3v);
        s  = s  * sc + (e0 + e1) + (e2 + e3);
        ax = ax * sc + (e0 * f0.x + e1 * f1.x) + (e2 * f2.x + e3 * f3.x);
        ay = ay * sc + (e0 * f0.y + e1 * f1.y) + (e2 * f2.y + e3 * f3.y);
        m = mn;
    }
    for (int j = cnt4; j < cnt; ++j) {
        int base = start + j;
        float a0 = alpha_perm[(size_t)base * 4 + h0];
        int s0 = src_perm[base];
        __half2 h0v = ((const __half2*)(xh16 + (size_t)s0 * HC))[l];
        float mn = fmaxf(a0, m);
        float e0 = __expf(a0 - mn);
        float sc = __expf(m - mn);
        float2 f0 = __half22float2(h0v);
        s  = s  * sc + e0;
        ax = ax * sc + e0 * f0.x;
        ay = ay * sc + e0 * f0.y;
        m = mn;
    }
    float inv = 1.f / (s + SOFT_EPS);
    ax *= inv; ay *= inv;
    // reduce over heads (lanes l, l^16, l^32, l^48 share channel pair l&15)
    ax += __shfl_xor(ax, 16, 64); ax += __shfl_xor(ax, 32, 64);
    ay += __shfl_xor(ay, 16, 64); ay += __shfl_xor(ay, 32, 64);
    if (l < 16) {
        int c0 = 2 * l;
        float r0 = 0.25f * ax + bias_conv[c0]     + bias_layer[c0];
        float r1 = 0.25f * ay + bias_conv[c0 + 1] + bias_layer[c0 + 1];
        float2 o2 = {fmaxf(r0, 0.f), fmaxf(r1, 0.f)};
        ((float2*)(out + (size_t)i * OUT_CH))[l] = o2;
    }
}

extern "C" void kernel_launch(void* const* d_in, const int* in_sizes, int n_in,
                              void* d_out, int out_size, void* d_ws, size_t ws_size,
                              hipStream_t stream) {
    const float* x          = (const float*)d_in[0];
    const float* edge_attr  = (const float*)d_in[1];
    const float* W          = (const float*)d_in[2];
    const float* W_edge     = (const float*)d_in[3];
    const float* att_src    = (const float*)d_in[4];
    const float* att_dst    = (const float*)d_in[5];
    const float* att_edge   = (const float*)d_in[6];
    const float* bias_conv  = (const float*)d_in[7];
    const float* bias_layer = (const float*)d_in[8];
    const int*   edge_index = (const int*)d_in[9];
    const int* srcI = edge_index;                // edge_index[0]
    const int* dstI = edge_index + N_EDGES;      // edge_index[1]
    float* out = (float*)d_out;

    char* ws = (char*)d_ws;
    size_t off = 0;
    auto carve = [&](size_t bytes) -> char* {
        char* p = ws + off;
        off += (bytes + 255) & ~(size_t)255;
        return p;
    };
    __half* xh16      = (__half*)carve((size_t)N_NODES * HC * 2);     // 12.8 MB
    float* alpha_perm = (float*)carve((size_t)N_EDGES * 4 * 4);       // 12.8 MB
    int*   src_perm   = (int*)carve((size_t)N_EDGES * 4);             // 3.2 MB
    float* a_src      = (float*)carve((size_t)N_NODES * 4 * 4);
    float* a_dst      = (float*)carve((size_t)N_NODES * 4 * 4);
    float* v_edge     = (float*)carve(4 * IN_CH * 4);
    int*   deg        = (int*)carve((size_t)N_NODES * 4);
    int*   offs       = (int*)carve((size_t)N_NODES * 4);
    int*   cursor     = (int*)carve((size_t)N_NODES * 4);
    int*   bsum       = (int*)carve(256 * 4);
    int*   bbase      = (int*)carve(256 * 4);

    hipMemsetAsync(deg, 0, (size_t)N_NODES * 4, stream);
    hipMemsetAsync(cursor, 0, (size_t)N_NODES * 4, stream);

    k_prep<<<1, 256, 0, stream>>>(W_edge, att_edge, v_edge);
    k_node<<<(N_NODES + 31) / 32, 256, 0, stream>>>(x, W, att_src, att_dst,
                                                    xh16, a_src, a_dst);
    k_deg<<<(N_EDGES + 255) / 256, 256, 0, stream>>>(dstI, deg);
    int nb = (N_NODES + 255) / 256;
    k_scan1<<<nb, 256, 0, stream>>>(deg, offs, bsum);
    k_scan2<<<1, 256, 0, stream>>>(bsum, bbase, nb);
    k_scan3<<<nb, 256, 0, stream>>>(offs, bbase);
    k_edge<<<(N_EDGES + 63) / 64, 256, 0, stream>>>(edge_attr, srcI, dstI, v_edge,
                                                    a_src, a_dst, offs, cursor,
                                                    alpha_perm, src_perm);
    k_aggr<<<(N_NODES + 3) / 4, 256, 0, stream>>>(alpha_perm, src_perm, offs, deg,
                                                  xh16, bias_conv, bias_layer, out);
}

// Round 3
// 224.813 us; speedup vs baseline: 1.4248x; 1.0972x over previous
//
#include <hip/hip_runtime.h>
#include <hip/hip_fp16.h>
#include <math.h>

#define N_NODES 50000
#define N_EDGES 800000
#define IN_CH 64
#define OUT_CH 32
#define HEADS 4
#define HC 128            // HEADS*OUT_CH
#define NEG_SLOPE 0.2f
#define SOFT_EPS 1e-16f
#define NEG_INF -3.402823466e38f

// ---------------- kernel 0: zero the degree histogram (no hipMemsetAsync!) --------
__global__ void k_zero(int* __restrict__ deg) {
    int i = blockIdx.x * 256 + threadIdx.x;
    if (i < N_NODES) deg[i] = 0;
}

// ---------------- kernel 1: fold W_edge x att_edge -> v_edge[4][64] ----------------
__global__ void k_prep(const float* __restrict__ W_edge,
                       const float* __restrict__ att_edge,
                       float* __restrict__ v_edge) {
    int t = threadIdx.x;          // 256 threads = 4 heads * 64 k
    int h = t >> 6, k = t & 63;
    float s = 0.f;
    #pragma unroll
    for (int c = 0; c < OUT_CH; ++c)
        s += att_edge[h * OUT_CH + c] * W_edge[(h * OUT_CH + c) * IN_CH + k];
    v_edge[h * IN_CH + k] = s;
}

// ---------------- kernel 2: xh16 = fp16(x @ W^T), plus per-node att scalars --------
__global__ __launch_bounds__(256) void k_node(const float* __restrict__ x,
                                              const float* __restrict__ W,
                                              const float* __restrict__ att_src,
                                              const float* __restrict__ att_dst,
                                              __half* __restrict__ xh16,
                                              float* __restrict__ a_src,
                                              float* __restrict__ a_dst) {
    __shared__ float Wl[HC * 65];          // +1 pad
    int tid = threadIdx.x;
    for (int i = tid; i < HC * IN_CH; i += 256)
        Wl[(i >> 6) * 65 + (i & 63)] = W[i];
    __syncthreads();

    int w = tid >> 6, l = tid & 63;
    float as0 = att_src[l], as1 = att_src[64 + l];
    float ad0 = att_dst[l], ad1 = att_dst[64 + l];
    int nbase = blockIdx.x * 32 + w * 8;

    for (int t = 0; t < 8; ++t) {
        int n = nbase + t;
        if (n >= N_NODES) break;
        const float4* xr = (const float4*)(x + (size_t)n * IN_CH);
        float4 A0 = {0, 0, 0, 0}, A1 = {0, 0, 0, 0};
        #pragma unroll
        for (int k4 = 0; k4 < 16; ++k4) {
            float4 xv = xr[k4];              // broadcast
            int k = k4 * 4;
            const float* w0 = &Wl[l * 65 + k];
            const float* w1 = &Wl[(64 + l) * 65 + k];
            A0.x += xv.x * w0[0]; A0.y += xv.y * w0[1];
            A0.z += xv.z * w0[2]; A0.w += xv.w * w0[3];
            A1.x += xv.x * w1[0]; A1.y += xv.y * w1[1];
            A1.z += xv.z * w1[2]; A1.w += xv.w * w1[3];
        }
        float acc0 = (A0.x + A0.y) + (A0.z + A0.w);
        float acc1 = (A1.x + A1.y) + (A1.z + A1.w);
        xh16[(size_t)n * HC + l]      = __float2half(acc0);
        xh16[(size_t)n * HC + 64 + l] = __float2half(acc1);

        float p  = acc0 * as0, q  = acc1 * as1;
        float pd = acc0 * ad0, qd = acc1 * ad1;
        #pragma unroll
        for (int m = 1; m <= 16; m <<= 1) {
            p  += __shfl_xor(p,  m, 64);
            q  += __shfl_xor(q,  m, 64);
            pd += __shfl_xor(pd, m, 64);
            qd += __shfl_xor(qd, m, 64);
        }
        if (l == 0) {
            a_src[n * 4 + 0] = p;  a_src[n * 4 + 2] = q;
            a_dst[n * 4 + 0] = pd; a_dst[n * 4 + 2] = qd;
        } else if (l == 32) {
            a_src[n * 4 + 1] = p;  a_src[n * 4 + 3] = q;
            a_dst[n * 4 + 1] = pd; a_dst[n * 4 + 3] = qd;
        }
    }
}

// ---------------- kernel 3: degree histogram ----------------
__global__ void k_deg(const int* __restrict__ dstI, int* __restrict__ deg) {
    int e = blockIdx.x * 256 + threadIdx.x;
    if (e < N_EDGES) atomicAdd(&deg[dstI[e]], 1);
}

// ---------------- scan kernels: exclusive prefix sum of deg -> offs ----------------
__global__ void k_scan1(const int* __restrict__ deg, int* __restrict__ offs,
                        int* __restrict__ bsum) {
    __shared__ int tmp[256];
    int t = threadIdx.x;
    int i = blockIdx.x * 256 + t;
    int v = (i < N_NODES) ? deg[i] : 0;
    tmp[t] = v;
    __syncthreads();
    #pragma unroll
    for (int off = 1; off < 256; off <<= 1) {
        int xv = (t >= off) ? tmp[t - off] : 0;
        __syncthreads();
        tmp[t] += xv;
        __syncthreads();
    }
    if (i < N_NODES) offs[i] = tmp[t] - v;    // exclusive
    if (t == 255) bsum[blockIdx.x] = tmp[t];
}

__global__ void k_scan2(const int* __restrict__ bsum, int* __restrict__ bbase, int nb) {
    __shared__ int tmp[256];
    int t = threadIdx.x;
    int v = (t < nb) ? bsum[t] : 0;
    tmp[t] = v;
    __syncthreads();
    #pragma unroll
    for (int off = 1; off < 256; off <<= 1) {
        int xv = (t >= off) ? tmp[t - off] : 0;
        __syncthreads();
        tmp[t] += xv;
        __syncthreads();
    }
    bbase[t] = tmp[t] - v;                    // exclusive
}

__global__ void k_scan3(int* __restrict__ offs, const int* __restrict__ bbase) {
    int i = blockIdx.x * 256 + threadIdx.x;
    if (i < N_NODES) offs[i] += bbase[blockIdx.x];
}

// ---------------- kernel 4: edge logits + fused CSR scatter ------------------------
// 4 threads per edge (part = head). Consumes offs via atomicAdd -> after this kernel
// offs[i] holds the INCLUSIVE end offset of segment i. No separate cursor array.
__global__ __launch_bounds__(256) void k_edge(const float* __restrict__ edge_attr,
                                              const int* __restrict__ srcI,
                                              const int* __restrict__ dstI,
                                              const float* __restrict__ v_edge,
                                              const float* __restrict__ a_src,
                                              const float* __restrict__ a_dst,
                                              int* __restrict__ offs,
                                              float* __restrict__ alpha_perm,
                                              int* __restrict__ src_perm) {
    __shared__ float vl[4 * IN_CH];
    int tid = threadIdx.x;
    vl[tid] = v_edge[tid];
    __syncthreads();
    int el = tid >> 2, part = tid & 3, l = tid & 63;
    long e = (long)blockIdx.x * 64 + el;
    if (e >= N_EDGES) return;

    const float4* ea = (const float4*)(edge_attr + e * IN_CH + part * 16);
    float4 v0 = ea[0], v1 = ea[1], v2 = ea[2], v3 = ea[3];
    float p[4];
    #pragma unroll
    for (int h = 0; h < 4; ++h) {
        const float* vr = vl + h * IN_CH + part * 16;
        p[h] = v0.x * vr[0]  + v0.y * vr[1]  + v0.z * vr[2]  + v0.w * vr[3]
             + v1.x * vr[4]  + v1.y * vr[5]  + v1.z * vr[6]  + v1.w * vr[7]
             + v2.x * vr[8]  + v2.y * vr[9]  + v2.z * vr[10] + v2.w * vr[11]
             + v3.x * vr[12] + v3.y * vr[13] + v3.z * vr[14] + v3.w * vr[15];
    }
    #pragma unroll
    for (int h = 0; h < 4; ++h) {
        p[h] += __shfl_xor(p[h], 1, 64);
        p[h] += __shfl_xor(p[h], 2, 64);
    }
    int d = dstI[e], s = srcI[e];
    float logit = a_src[d * 4 + part] + a_dst[s * 4 + part] + p[part];
    float lr = logit > 0.f ? logit : NEG_SLOPE * logit;

    int pos = 0;
    if (part == 0) pos = atomicAdd(&offs[d], 1);
    pos = __shfl(pos, l & ~3, 64);            // broadcast from part==0 lane
    alpha_perm[(size_t)pos * 4 + part] = lr;
    if (part == 0) src_perm[pos] = s;
}

// ---------------- kernel 5: single-pass online softmax + aggregation ---------------
// One 64-lane wave per dst node. Lane l owns channels (2l,2l+1); head h0 = l>>4.
// offs now holds inclusive end offsets: start = offs[i-1] (0 for i==0), end = offs[i].
__global__ __launch_bounds__(256) void k_aggr(const float* __restrict__ alpha_perm,
                                              const int* __restrict__ src_perm,
                                              const int* __restrict__ offs,
                                              const __half* __restrict__ xh16,
                                              const float* __restrict__ bias_conv,
                                              const float* __restrict__ bias_layer,
                                              float* __restrict__ out) {
    int w = threadIdx.x >> 6, l = threadIdx.x & 63;
    int i = blockIdx.x * 4 + w;
    if (i >= N_NODES) return;
    int start = (i == 0) ? 0 : offs[i - 1];
    int cnt = offs[i] - start;
    int h0 = l >> 4;

    float m = NEG_INF, s = 0.f, ax = 0.f, ay = 0.f;
    int cnt4 = cnt & ~3;
    for (int j = 0; j < cnt4; j += 4) {
        int base = start + j;
        float a0 = alpha_perm[(size_t)(base + 0) * 4 + h0];
        float a1 = alpha_perm[(size_t)(base + 1) * 4 + h0];
        float a2 = alpha_perm[(size_t)(base + 2) * 4 + h0];
        float a3 = alpha_perm[(size_t)(base + 3) * 4 + h0];
        int s0 = src_perm[base + 0], s1 = src_perm[base + 1];
        int s2 = src_perm[base + 2], s3 = src_perm[base + 3];
        __half2 h0v = ((const __half2*)(xh16 + (size_t)s0 * HC))[l];
        __half2 h1v = ((const __half2*)(xh16 + (size_t)s1 * HC))[l];
        __half2 h2v = ((const __half2*)(xh16 + (size_t)s2 * HC))[l];
        __half2 h3v = ((const __half2*)(xh16 + (size_t)s3 * HC))[l];
        float mn = fmaxf(fmaxf(fmaxf(a0, a1), fmaxf(a2, a3)), m);
        float e0 = __expf(a0 - mn), e1 = __expf(a1 - mn);
        float e2 = __expf(a2 - mn), e3 = __expf(a3 - mn);
        float sc = __expf(m - mn);
        float2 f0 = __half22float2(h0v), f1 = __half22float2(h1v);
        float2 f2 = __half22float2(h2v), f3 = __half22float2(h3v);
        s  = s  * sc + (e0 + e1) + (e2 + e3);
        ax = ax * sc + (e0 * f0.x + e1 * f1.x) + (e2 * f2.x + e3 * f3.x);
        ay = ay * sc + (e0 * f0.y + e1 * f1.y) + (e2 * f2.y + e3 * f3.y);
        m = mn;
    }
    for (int j = cnt4; j < cnt; ++j) {
        int base = start + j;
        float a0 = alpha_perm[(size_t)base * 4 + h0];
        int s0 = src_perm[base];
        __half2 h0v = ((const __half2*)(xh16 + (size_t)s0 * HC))[l];
        float mn = fmaxf(a0, m);
        float e0 = __expf(a0 - mn);
        float sc = __expf(m - mn);
        float2 f0 = __half22float2(h0v);
        s  = s  * sc + e0;
        ax = ax * sc + e0 * f0.x;
        ay = ay * sc + e0 * f0.y;
        m = mn;
    }
    float inv = 1.f / (s + SOFT_EPS);
    ax *= inv; ay *= inv;
    // reduce over heads (lanes l, l^16, l^32, l^48 share channel pair l&15)
    ax += __shfl_xor(ax, 16, 64); ax += __shfl_xor(ax, 32, 64);
    ay += __shfl_xor(ay, 16, 64); ay += __shfl_xor(ay, 32, 64);
    if (l < 16) {
        int c0 = 2 * l;
        float r0 = 0.25f * ax + bias_conv[c0]     + bias_layer[c0];
        float r1 = 0.25f * ay + bias_conv[c0 + 1] + bias_layer[c0 + 1];
        float2 o2 = {fmaxf(r0, 0.f), fmaxf(r1, 0.f)};
        ((float2*)(out + (size_t)i * OUT_CH))[l] = o2;
    }
}

extern "C" void kernel_launch(void* const* d_in, const int* in_sizes, int n_in,
                              void* d_out, int out_size, void* d_ws, size_t ws_size,
                              hipStream_t stream) {
    const float* x          = (const float*)d_in[0];
    const float* edge_attr  = (const float*)d_in[1];
    const float* W          = (const float*)d_in[2];
    const float* W_edge     = (const float*)d_in[3];
    const float* att_src    = (const float*)d_in[4];
    const float* att_dst    = (const float*)d_in[5];
    const float* att_edge   = (const float*)d_in[6];
    const float* bias_conv  = (const float*)d_in[7];
    const float* bias_layer = (const float*)d_in[8];
    const int*   edge_index = (const int*)d_in[9];
    const int* srcI = edge_index;                // edge_index[0]
    const int* dstI = edge_index + N_EDGES;      // edge_index[1]
    float* out = (float*)d_out;

    char* ws = (char*)d_ws;
    size_t off = 0;
    auto carve = [&](size_t bytes) -> char* {
        char* p = ws + off;
        off += (bytes + 255) & ~(size_t)255;
        return p;
    };
    __half* xh16      = (__half*)carve((size_t)N_NODES * HC * 2);     // 12.8 MB
    float* alpha_perm = (float*)carve((size_t)N_EDGES * 4 * 4);       // 12.8 MB
    int*   src_perm   = (int*)carve((size_t)N_EDGES * 4);             // 3.2 MB
    float* a_src      = (float*)carve((size_t)N_NODES * 4 * 4);
    float* a_dst      = (float*)carve((size_t)N_NODES * 4 * 4);
    float* v_edge     = (float*)carve(4 * IN_CH * 4);
    int*   deg        = (int*)carve((size_t)N_NODES * 4);
    int*   offs       = (int*)carve((size_t)N_NODES * 4);
    int*   bsum       = (int*)carve(256 * 4);
    int*   bbase      = (int*)carve(256 * 4);

    int nb = (N_NODES + 255) / 256;
    k_zero<<<nb, 256, 0, stream>>>(deg);
    k_prep<<<1, 256, 0, stream>>>(W_edge, att_edge, v_edge);
    k_node<<<(N_NODES + 31) / 32, 256, 0, stream>>>(x, W, att_src, att_dst,
                                                    xh16, a_src, a_dst);
    k_deg<<<(N_EDGES + 255) / 256, 256, 0, stream>>>(dstI, deg);
    k_scan1<<<nb, 256, 0, stream>>>(deg, offs, bsum);
    k_scan2<<<1, 256, 0, stream>>>(bsum, bbase, nb);
    k_scan3<<<nb, 256, 0, stream>>>(offs, bbase);
    k_edge<<<(N_EDGES + 63) / 64, 256, 0, stream>>>(edge_attr, srcI, dstI, v_edge,
                                                    a_src, a_dst, offs,
                                                    alpha_perm, src_perm);
    k_aggr<<<(N_NODES + 3) / 4, 256, 0, stream>>>(alpha_perm, src_perm, offs,
                                                  xh16, bias_conv, bias_layer, out);
}